// Round 10
// baseline (5322.901 us; speedup 1.0000x reference)
//
#include <hip/hip_runtime.h>

typedef unsigned short ushort_t;
typedef unsigned int   uint_t;
typedef short bf16x8 __attribute__((ext_vector_type(8)));
typedef float f32x4  __attribute__((ext_vector_type(4)));

#define MFMA16(a,b,c) __builtin_amdgcn_mfma_f32_16x16x32_bf16((a),(b),(c),0,0,0)

static __device__ __forceinline__ float bf2f(ushort_t b) {
  union { uint_t u; float f; } v; v.u = ((uint_t)b) << 16; return v.f;
}
static __device__ __forceinline__ ushort_t f2bf(float f) {
  union { float f; uint_t u; } v; v.f = f;
  uint_t r = v.u + 0x7fffu + ((v.u >> 16) & 1u);
  return (ushort_t)(r >> 16);
}
static __device__ __forceinline__ float frcp(float x) { return __builtin_amdgcn_rcpf(x); }
static __device__ __forceinline__ float sigm(float x) { return frcp(1.0f + __expf(-x)); }
static __device__ __forceinline__ float ftanh(float x) { return 1.0f - 2.0f * frcp(1.0f + __expf(2.0f * x)); }
static __device__ __forceinline__ float selu_f(float x) {
  float e = 1.6732632423543772f * (__expf(x) - 1.0f);
  return 1.0507009873554805f * (x > 0.0f ? x : e);
}
static __device__ __forceinline__ bf16x8 pack8(float4 a, float4 b) {
  bf16x8 r;
  r[0] = (short)f2bf(a.x); r[1] = (short)f2bf(a.y); r[2] = (short)f2bf(a.z); r[3] = (short)f2bf(a.w);
  r[4] = (short)f2bf(b.x); r[5] = (short)f2bf(b.y); r[6] = (short)f2bf(b.z); r[7] = (short)f2bf(b.w);
  return r;
}
static __device__ __forceinline__ void split8(float4 a, float4 b, bf16x8& hi, bf16x8& lo) {
  hi = pack8(a, b);
  float4 ra, rb;
  ra.x = a.x - bf2f((ushort_t)hi[0]); ra.y = a.y - bf2f((ushort_t)hi[1]);
  ra.z = a.z - bf2f((ushort_t)hi[2]); ra.w = a.w - bf2f((ushort_t)hi[3]);
  rb.x = b.x - bf2f((ushort_t)hi[4]); rb.y = b.y - bf2f((ushort_t)hi[5]);
  rb.z = b.z - bf2f((ushort_t)hi[6]); rb.w = b.w - bf2f((ushort_t)hi[7]);
  lo = pack8(ra, rb);
}

#define GFRAG(ptr, f) (*(const bf16x8*)&(ptr)[(((f) * 64 + lane)) * 8])
#define LFRAG(arr, f) (*(const bf16x8*)&(arr)[(((f) * 64 + lane)) * 8])

// ---------------------------------------------------------------------------
__global__ void detect_dtype(const uint_t* __restrict__ caps, int* __restrict__ flag) {
  int lane = threadIdx.x;
  uint_t d = caps[lane];
  uint_t lo = d & 0xFFFFu, hi = d >> 16;
  bool isbf = (lo >= 0x3F00u && lo <= 0x3FC0u) && (hi >= 0x3F00u && hi <= 0x3FC0u);
  unsigned long long m = __ballot(isbf);
  if (lane == 0) *flag = (__popcll(m) >= 48) ? 1 : 0;
}

// ---------------------------------------------------------------------------
#define NARR 14
struct ConvDesc {
  const void* src[NARR];
  float*      dst[NARR];
  int         n[NARR];
  int         blk0[NARR + 1];
};
__global__ void conv_all(ConvDesc d, const int* __restrict__ flag) {
  int isbf = *flag;
  int b = blockIdx.x;
  int a = 0;
  while (a + 1 < NARR && b >= d.blk0[a + 1]) ++a;
  int idx = (b - d.blk0[a]) * 256 + threadIdx.x;
  if (idx >= d.n[a]) return;
  d.dst[a][idx] = isbf ? bf2f(((const ushort_t*)d.src[a])[idx])
                       : ((const float*)d.src[a])[idx];
}

// ---------------------------------------------------------------------------
struct PackAll {
  const float* A[8];
  const float* B[8];
  ushort_t* dH[8];
  ushort_t* dL[8];
  int srcN[8], colOff[8], splitK[8], nCk[8], NT[8], blk0[9];
};
__global__ void pack_all(PackAll P) {
  int b = blockIdx.x;
  int a = 0;
  while (a + 1 < 8 && b >= P.blk0[a + 1]) ++a;
  int i = (b - P.blk0[a]) * 256 + threadIdx.x;
  int j = i & 7;
  int lane = (i >> 3) & 63;
  int f = i >> 9;
  int c = f / P.NT[a], nt = f - c * P.NT[a];
  int k = c * 32 + ((lane >> 4) << 3) + j;
  int n = P.colOff[a] + nt * 16 + (lane & 15);
  float v = (k < P.splitK[a]) ? P.A[a][k * P.srcN[a] + n]
                              : P.B[a][(k - P.splitK[a]) * P.srcN[a] + n];
  ushort_t hi = f2bf(v);
  P.dH[a][i] = hi;
  P.dL[a][i] = f2bf(v - bf2f(hi));
}

// ---------------------------------------------------------------------------
__global__ void init_states(const float* __restrict__ caps, const float* __restrict__ traffic,
                            ushort_t* __restrict__ linkHL,
                            float* __restrict__ path_state, int n_links, int n_paths) {
  long i = (long)blockIdx.x * 256 + threadIdx.x;
  long total = (long)(n_links + n_paths) * 64;
  if (i >= total) return;
  int row = (int)(i >> 6), col = (int)(i & 63);
  if (row < n_links) {
    float v = (col == 0) ? caps[row] : 0.0f;
    ushort_t hi = f2bf(v);
    linkHL[(long)row * 128 + col] = hi;
    linkHL[(long)row * 128 + 64 + col] = f2bf(v - bf2f(hi));
  } else {
    int pr = row - n_links;
    path_state[(long)pr * 64 + col] = (col == 0) ? traffic[pr] : 0.0f;
  }
}

// ---------------------------------------------------------------------------
__global__ void hist_k(const int* __restrict__ links, int* __restrict__ cnt, int E) {
  int e = blockIdx.x * 256 + threadIdx.x;
  if (e < E) atomicAdd(&cnt[links[e]], 1);
}
__global__ void scan_k(const int* __restrict__ cnt, int* __restrict__ base,
                       int* __restrict__ cursor, int n) {
  __shared__ int part[256];
  int tid = threadIdx.x;
  int chunk = (n + 255) / 256;
  int lo = tid * chunk, hiEnd = lo + chunk; if (hiEnd > n) hiEnd = n;
  int s = 0;
  for (int i = lo; i < hiEnd; ++i) s += cnt[i];
  part[tid] = s;
  __syncthreads();
  if (tid == 0) { int acc = 0; for (int i = 0; i < 256; ++i) { int v = part[i]; part[i] = acc; acc += v; } }
  __syncthreads();
  int acc = part[tid];
  for (int i = lo; i < hiEnd; ++i) { base[i] = acc; cursor[i] = acc; acc += cnt[i]; }
}
__global__ void fill_k(const int* __restrict__ links, int* __restrict__ cursor,
                       int* __restrict__ pos_of, int E) {
  int e = blockIdx.x * 256 + threadIdx.x;
  if (e >= E) return;
  pos_of[e] = atomicAdd(&cursor[links[e]], 1);
}

// ---------------------------------------------------------------------------
// Aggregate bf16 m (CSR-ordered, contiguous per link) -> fp32 agg.
__global__ __launch_bounds__(256) void agg_kernel(
    const ushort_t* __restrict__ mH,
    const int* __restrict__ base, const int* __restrict__ cnt,
    float* __restrict__ agg, int n_links) {
  int l = blockIdx.x * 4 + (threadIdx.x >> 6);
  if (l >= n_links) return;
  int lane = threadIdx.x & 63;
  int s = base[l], d = cnt[l];
  float acc0 = 0.0f, acc1 = 0.0f;
  int i = 0;
  for (; i + 2 <= d; i += 2) {
    acc0 += bf2f(mH[(long)(s + i) * 64 + lane]);
    acc1 += bf2f(mH[(long)(s + i + 1) * 64 + lane]);
  }
  if (i < d) acc0 += bf2f(mH[(long)(s + i) * 64 + lane]);
  agg[(long)l * 64 + lane] = acc0 + acc1;
}

// ---------------------------------------------------------------------------
// Path GRU, bf16-dataset variant (flag==1). Dormant for fp32 datasets.
#define PWB 7
__global__ __launch_bounds__(448) void path_kernel_bf16(
    const int* __restrict__ links,
    const ushort_t* __restrict__ linkHL,
    float* __restrict__ path_state,
    ushort_t* __restrict__ mH, int mmode, int store_m,
    const int* __restrict__ pos_of, float* __restrict__ agg,
    const ushort_t* __restrict__ wzrH, const ushort_t* __restrict__ wcH,
    const float* __restrict__ bp, const int* __restrict__ flagp, int n_paths) {
  __shared__ __align__(16) ushort_t s_wzr[32 * 512];
  __shared__ __align__(16) ushort_t s_wc[16 * 512];
  __shared__ __align__(16) ushort_t s_hh[PWB][16][68];
  __shared__ __align__(16) ushort_t s_hl[PWB][16][68];
  __shared__ float s_bias[192];

  if (flagp[0] == 0) return;

  int tid = threadIdx.x;
  {
    uint_t* s0 = (uint_t*)s_wzr; const uint_t* g0 = (const uint_t*)wzrH;
    for (int i = tid; i < 8192; i += 448) s0[i] = g0[i];
    uint_t* s1 = (uint_t*)s_wc;  const uint_t* g1 = (const uint_t*)wcH;
    for (int i = tid; i < 4096; i += 448) s1[i] = g1[i];
    for (int i = tid; i < 192; i += 448) s_bias[i] = bp[i];
  }

  int wv = tid >> 6, lane = tid & 63, l15 = lane & 15, quad = lane >> 4;
  int p0 = (blockIdx.x * PWB + wv) * 16;
  bool valid = (p0 < n_paths);

  float h[4][4];
  if (valid) {
#pragma unroll
    for (int tt = 0; tt < 4; ++tt)
#pragma unroll
      for (int r = 0; r < 4; ++r) {
        float v = path_state[(long)(p0 + quad * 4 + r) * 64 + tt * 16 + l15];
        h[tt][r] = v;
        ushort_t hi = f2bf(v);
        s_hh[wv][quad * 4 + r][tt * 16 + l15] = hi;
        s_hl[wv][quad * 4 + r][tt * 16 + l15] = f2bf(v - bf2f(hi));
      }
  }
  __syncthreads();
  if (!valid) return;

  for (int t = 0; t < 8; ++t) {
    int la = links[(p0 + l15) * 8 + t];
    const ushort_t* xr = linkHL + (long)la * 128;
    bf16x8 axH0 = *(const bf16x8*)(xr + quad * 8);
    bf16x8 axH1 = *(const bf16x8*)(xr + 32 + quad * 8);
    bf16x8 axL0 = *(const bf16x8*)(xr + 64 + quad * 8);
    bf16x8 axL1 = *(const bf16x8*)(xr + 96 + quad * 8);
    bf16x8 ahH0 = *(const bf16x8*)&s_hh[wv][l15][quad * 8];
    bf16x8 ahH1 = *(const bf16x8*)&s_hh[wv][l15][32 + quad * 8];
    bf16x8 ahL0 = *(const bf16x8*)&s_hl[wv][l15][quad * 8];
    bf16x8 ahL1 = *(const bf16x8*)&s_hl[wv][l15][32 + quad * 8];

    f32x4 azr[8];
#pragma unroll
    for (int nt = 0; nt < 8; ++nt) {
      f32x4 acc = {0.f, 0.f, 0.f, 0.f};
      acc = MFMA16(axH0, LFRAG(s_wzr, nt), acc);
      acc = MFMA16(axH1, LFRAG(s_wzr, 8 + nt), acc);
      acc = MFMA16(ahH0, LFRAG(s_wzr, 16 + nt), acc);
      acc = MFMA16(ahH1, LFRAG(s_wzr, 24 + nt), acc);
      acc = MFMA16(axL0, LFRAG(s_wzr, nt), acc);
      acc = MFMA16(axL1, LFRAG(s_wzr, 8 + nt), acc);
      acc = MFMA16(ahL0, LFRAG(s_wzr, 16 + nt), acc);
      acc = MFMA16(ahL1, LFRAG(s_wzr, 24 + nt), acc);
      azr[nt] = acc;
    }
    f32x4 axc[4], ahc[4];
#pragma unroll
    for (int nt = 0; nt < 4; ++nt) {
      f32x4 a = {0.f, 0.f, 0.f, 0.f};
      a = MFMA16(axH0, LFRAG(s_wc, nt), a);
      a = MFMA16(axH1, LFRAG(s_wc, 4 + nt), a);
      a = MFMA16(axL0, LFRAG(s_wc, nt), a);
      a = MFMA16(axL1, LFRAG(s_wc, 4 + nt), a);
      axc[nt] = a;
      f32x4 b = {0.f, 0.f, 0.f, 0.f};
      b = MFMA16(ahH0, LFRAG(s_wc, 8 + nt), b);
      b = MFMA16(ahH1, LFRAG(s_wc, 12 + nt), b);
      b = MFMA16(ahL0, LFRAG(s_wc, 8 + nt), b);
      b = MFMA16(ahL1, LFRAG(s_wc, 12 + nt), b);
      ahc[nt] = b;
    }

    int pr[4] = {0, 0, 0, 0};
    if (store_m) {
      if (mmode == 2) {
#pragma unroll
        for (int r = 0; r < 4; ++r) pr[r] = links[(p0 + quad * 4 + r) * 8 + t];
      } else {
#pragma unroll
        for (int r = 0; r < 4; ++r) pr[r] = pos_of[(p0 + quad * 4 + r) * 8 + t];
      }
    }

#pragma unroll
    for (int tt = 0; tt < 4; ++tt) {
      int col = tt * 16 + l15;
      float bz = s_bias[col], br = s_bias[64 + col], bc = s_bias[128 + col];
#pragma unroll
      for (int r = 0; r < 4; ++r) {
        float z   = sigm(azr[tt][r] + bz);
        float rr  = sigm(azr[4 + tt][r] + br);
        float hcv = ftanh(axc[tt][r] + bc + rr * ahc[tt][r]);
        float hn  = z * h[tt][r] + (1.0f - z) * hcv;
        h[tt][r] = hn;
        if (store_m) {
          if (mmode == 1) mH[(long)pr[r] * 64 + col] = f2bf(hn);
          else atomicAdd(&agg[(long)pr[r] * 64 + col], hn);
        }
        ushort_t hi = f2bf(hn);
        s_hh[wv][quad * 4 + r][col] = hi;
        s_hl[wv][quad * 4 + r][col] = f2bf(hn - bf2f(hi));
      }
    }
  }

#pragma unroll
  for (int tt = 0; tt < 4; ++tt)
#pragma unroll
    for (int r = 0; r < 4; ++r)
      path_state[(long)(p0 + quad * 4 + r) * 64 + tt * 16 + l15] = h[tt][r];
}

// ---------------------------------------------------------------------------
// Path GRU, fp32-dataset variant: 13 waves (832 thr, 159 KB LDS), grid-stride.
// m stored bf16 at CSR slot via s_hh round-trip -> 16-B/lane coalesced stores
// (full 128-B row segments, no partial-sector RMW; was 398 MB WRITE vs 127
// logical with 2-B scattered stores, measured r7/r9).
#define PW 13
__global__ __launch_bounds__(832) void path_kernel_f32(
    const int* __restrict__ links,
    const ushort_t* __restrict__ linkHL,
    float* __restrict__ path_state,
    ushort_t* __restrict__ mH, int mmode, int store_m,
    const int* __restrict__ pos_of, float* __restrict__ agg,
    const ushort_t* __restrict__ wzrH, const ushort_t* __restrict__ wzrL,
    const ushort_t* __restrict__ wcH,  const ushort_t* __restrict__ wcL,
    const float* __restrict__ bp, const int* __restrict__ flagp,
    int n_paths, int nGroups) {
  __shared__ __align__(16) ushort_t s_wzr[2][32 * 512];
  __shared__ __align__(16) ushort_t s_wc[2][16 * 512];
  __shared__ __align__(16) ushort_t s_hh[PW][16][72];
  __shared__ __align__(16) ushort_t s_hl[PW][16][72];
  __shared__ float s_bias[192];

  if (flagp[0] != 0) return;

  int tid = threadIdx.x;
  {
    uint_t* s0 = (uint_t*)s_wzr[0]; const uint_t* g0 = (const uint_t*)wzrH;
    for (int i = tid; i < 8192; i += 832) s0[i] = g0[i];
    uint_t* s1 = (uint_t*)s_wc[0];  const uint_t* g1 = (const uint_t*)wcH;
    for (int i = tid; i < 4096; i += 832) s1[i] = g1[i];
    uint_t* s2 = (uint_t*)s_wzr[1]; const uint_t* g2 = (const uint_t*)wzrL;
    for (int i = tid; i < 8192; i += 832) s2[i] = g2[i];
    uint_t* s3 = (uint_t*)s_wc[1];  const uint_t* g3 = (const uint_t*)wcL;
    for (int i = tid; i < 4096; i += 832) s3[i] = g3[i];
    for (int i = tid; i < 192; i += 832) s_bias[i] = bp[i];
  }
  __syncthreads();

  int wv = tid >> 6, lane = tid & 63, l15 = lane & 15, quad = lane >> 4;
  int mrow0 = lane >> 3;          // rows this lane stores (mrow0, mrow0+8)
  int mcol0 = (lane & 7) * 8;     // 8 bf16 = 16 B per row segment

  for (int g = 0; g < nGroups; ++g) {
    int slot = g * gridDim.x + blockIdx.x;
    int p0 = (slot * PW + wv) * 16;
    if (p0 >= n_paths) continue;

    float h[4][4];
#pragma unroll
    for (int tt = 0; tt < 4; ++tt)
#pragma unroll
      for (int r = 0; r < 4; ++r) {
        float v = path_state[(long)(p0 + quad * 4 + r) * 64 + tt * 16 + l15];
        h[tt][r] = v;
        ushort_t hi = f2bf(v);
        s_hh[wv][quad * 4 + r][tt * 16 + l15] = hi;
        s_hl[wv][quad * 4 + r][tt * 16 + l15] = f2bf(v - bf2f(hi));
      }

    const int* lrow = links + (long)(p0 + l15) * 8;
    {
      int la0 = lrow[0];
      const ushort_t* x0 = linkHL + (long)la0 * 128;
      bf16x8 nH0 = *(const bf16x8*)(x0 + quad * 8);
      bf16x8 nH1 = *(const bf16x8*)(x0 + 32 + quad * 8);
      bf16x8 nL0 = *(const bf16x8*)(x0 + 64 + quad * 8);
      bf16x8 nL1 = *(const bf16x8*)(x0 + 96 + quad * 8);

      for (int t = 0; t < 8; ++t) {
        bf16x8 axH0 = nH0, axH1 = nH1, axL0 = nL0, axL1 = nL1;
        if (t < 7) {
          int la2 = lrow[t + 1];
          const ushort_t* x2 = linkHL + (long)la2 * 128;
          nH0 = *(const bf16x8*)(x2 + quad * 8);
          nH1 = *(const bf16x8*)(x2 + 32 + quad * 8);
          nL0 = *(const bf16x8*)(x2 + 64 + quad * 8);
          nL1 = *(const bf16x8*)(x2 + 96 + quad * 8);
        }
        // hoisted store-slot loads (used ~1500 cyc later)
        int pr2[2] = {0, 0};
        int pr[4] = {0, 0, 0, 0};
        if (store_m) {
          if (mmode == 2) {
#pragma unroll
            for (int r = 0; r < 4; ++r) pr[r] = links[(long)(p0 + quad * 4 + r) * 8 + t];
          } else {
            pr2[0] = pos_of[(long)(p0 + mrow0) * 8 + t];
            pr2[1] = pos_of[(long)(p0 + mrow0 + 8) * 8 + t];
          }
        }
        bf16x8 ahH0 = *(const bf16x8*)&s_hh[wv][l15][quad * 8];
        bf16x8 ahH1 = *(const bf16x8*)&s_hh[wv][l15][32 + quad * 8];
        bf16x8 ahL0 = *(const bf16x8*)&s_hl[wv][l15][quad * 8];
        bf16x8 ahL1 = *(const bf16x8*)&s_hl[wv][l15][32 + quad * 8];

        f32x4 azr[8];
#pragma unroll
        for (int nt = 0; nt < 8; ++nt) {
          f32x4 acc = {0.f, 0.f, 0.f, 0.f};
          acc = MFMA16(axH0, LFRAG(s_wzr[0], nt), acc);
          acc = MFMA16(axH1, LFRAG(s_wzr[0], 8 + nt), acc);
          acc = MFMA16(axL0, LFRAG(s_wzr[0], nt), acc);
          acc = MFMA16(axL1, LFRAG(s_wzr[0], 8 + nt), acc);
          acc = MFMA16(axH0, LFRAG(s_wzr[1], nt), acc);
          acc = MFMA16(axH1, LFRAG(s_wzr[1], 8 + nt), acc);
          acc = MFMA16(ahH0, LFRAG(s_wzr[0], 16 + nt), acc);
          acc = MFMA16(ahH1, LFRAG(s_wzr[0], 24 + nt), acc);
          acc = MFMA16(ahL0, LFRAG(s_wzr[0], 16 + nt), acc);
          acc = MFMA16(ahL1, LFRAG(s_wzr[0], 24 + nt), acc);
          acc = MFMA16(ahH0, LFRAG(s_wzr[1], 16 + nt), acc);
          acc = MFMA16(ahH1, LFRAG(s_wzr[1], 24 + nt), acc);
          azr[nt] = acc;
        }
        f32x4 axc[4], ahc[4];
#pragma unroll
        for (int nt = 0; nt < 4; ++nt) {
          f32x4 a = {0.f, 0.f, 0.f, 0.f};
          a = MFMA16(axH0, LFRAG(s_wc[0], nt), a);
          a = MFMA16(axH1, LFRAG(s_wc[0], 4 + nt), a);
          a = MFMA16(axL0, LFRAG(s_wc[0], nt), a);
          a = MFMA16(axL1, LFRAG(s_wc[0], 4 + nt), a);
          a = MFMA16(axH0, LFRAG(s_wc[1], nt), a);
          a = MFMA16(axH1, LFRAG(s_wc[1], 4 + nt), a);
          axc[nt] = a;
          f32x4 b = {0.f, 0.f, 0.f, 0.f};
          b = MFMA16(ahH0, LFRAG(s_wc[0], 8 + nt), b);
          b = MFMA16(ahH1, LFRAG(s_wc[0], 12 + nt), b);
          b = MFMA16(ahL0, LFRAG(s_wc[0], 8 + nt), b);
          b = MFMA16(ahL1, LFRAG(s_wc[0], 12 + nt), b);
          b = MFMA16(ahH0, LFRAG(s_wc[1], 8 + nt), b);
          b = MFMA16(ahH1, LFRAG(s_wc[1], 12 + nt), b);
          ahc[nt] = b;
        }

#pragma unroll
        for (int tt = 0; tt < 4; ++tt) {
          int col = tt * 16 + l15;
          float bz = s_bias[col], br = s_bias[64 + col], bc = s_bias[128 + col];
#pragma unroll
          for (int r = 0; r < 4; ++r) {
            float z   = sigm(azr[tt][r] + bz);
            float rr  = sigm(azr[4 + tt][r] + br);
            float hcv = ftanh(axc[tt][r] + bc + rr * ahc[tt][r]);
            float hn  = z * h[tt][r] + (1.0f - z) * hcv;
            h[tt][r] = hn;
            if (store_m && mmode == 2) atomicAdd(&agg[(long)pr[r] * 64 + col], hn);
            ushort_t hi = f2bf(hn);
            s_hh[wv][quad * 4 + r][col] = hi;
            s_hl[wv][quad * 4 + r][col] = f2bf(hn - bf2f(hi));
          }
        }

        // m-row store from s_hh (same wave wrote it just above; lockstep LDS
        // RAW, same pattern as the cross-step s_hh reuse). 8 lanes x 16 B per
        // 128-B row -> full sectors, no RMW.
        if (store_m && mmode == 1) {
          bf16x8 v0 = *(const bf16x8*)&s_hh[wv][mrow0][mcol0];
          bf16x8 v1 = *(const bf16x8*)&s_hh[wv][mrow0 + 8][mcol0];
          *(bf16x8*)&mH[(long)pr2[0] * 64 + mcol0] = v0;
          *(bf16x8*)&mH[(long)pr2[1] * 64 + mcol0] = v1;
        }
      }
    }

#pragma unroll
    for (int tt = 0; tt < 4; ++tt)
#pragma unroll
      for (int r = 0; r < 4; ++r)
        path_state[(long)(p0 + quad * 4 + r) * 64 + tt * 16 + l15] = h[tt][r];
  }
}

// ---------------------------------------------------------------------------
__global__ __launch_bounds__(320) void link_kernel(
    const float* __restrict__ agg,
    ushort_t* __restrict__ linkHL,
    const ushort_t* __restrict__ wzrH, const ushort_t* __restrict__ wzrL,
    const ushort_t* __restrict__ wcH,  const ushort_t* __restrict__ wcL,
    const float* __restrict__ be, const int* __restrict__ flagp) {
  __shared__ __align__(16) ushort_t s_wzr[2][32 * 512];
  __shared__ __align__(16) ushort_t s_wc[2][16 * 512];
  __shared__ float s_bias[192];

  int tid = threadIdx.x;
  int wlo = (flagp[0] == 0) ? 1 : 0;
  {
    uint_t* s0 = (uint_t*)s_wzr[0]; const uint_t* g0 = (const uint_t*)wzrH;
    for (int i = tid; i < 8192; i += 320) s0[i] = g0[i];
    uint_t* s1 = (uint_t*)s_wc[0];  const uint_t* g1 = (const uint_t*)wcH;
    for (int i = tid; i < 4096; i += 320) s1[i] = g1[i];
    if (wlo) {
      uint_t* s2 = (uint_t*)s_wzr[1]; const uint_t* g2 = (const uint_t*)wzrL;
      for (int i = tid; i < 8192; i += 320) s2[i] = g2[i];
      uint_t* s3 = (uint_t*)s_wc[1];  const uint_t* g3 = (const uint_t*)wcL;
      for (int i = tid; i < 4096; i += 320) s3[i] = g3[i];
    }
    for (int i = tid; i < 192; i += 320) s_bias[i] = be[i];
  }
  __syncthreads();

  int wv = tid >> 6, lane = tid & 63, l15 = lane & 15, quad = lane >> 4;
  int l0 = (blockIdx.x * 5 + wv) * 16;

  const float* arow = agg + (long)(l0 + l15) * 64;
  float4 f0 = *(const float4*)(arow + quad * 8);
  float4 f1 = *(const float4*)(arow + quad * 8 + 4);
  float4 f2 = *(const float4*)(arow + 32 + quad * 8);
  float4 f3 = *(const float4*)(arow + 36 + quad * 8);
  bf16x8 axH0, axL0, axH1, axL1;
  split8(f0, f1, axH0, axL0);
  split8(f2, f3, axH1, axL1);
  const ushort_t* hr = linkHL + (long)(l0 + l15) * 128;
  bf16x8 ahH0 = *(const bf16x8*)(hr + quad * 8);
  bf16x8 ahH1 = *(const bf16x8*)(hr + 32 + quad * 8);
  bf16x8 ahL0 = *(const bf16x8*)(hr + 64 + quad * 8);
  bf16x8 ahL1 = *(const bf16x8*)(hr + 96 + quad * 8);

  float h[4][4];
#pragma unroll
  for (int tt = 0; tt < 4; ++tt)
#pragma unroll
    for (int r = 0; r < 4; ++r) {
      long row = (long)(l0 + quad * 4 + r) * 128;
      int col = tt * 16 + l15;
      h[tt][r] = bf2f(linkHL[row + col]) + bf2f(linkHL[row + 64 + col]);
    }

  f32x4 azr[8];
#pragma unroll
  for (int nt = 0; nt < 8; ++nt) {
    f32x4 acc = {0.f, 0.f, 0.f, 0.f};
    acc = MFMA16(axH0, LFRAG(s_wzr[0], nt), acc);
    acc = MFMA16(axH1, LFRAG(s_wzr[0], 8 + nt), acc);
    acc = MFMA16(ahH0, LFRAG(s_wzr[0], 16 + nt), acc);
    acc = MFMA16(ahH1, LFRAG(s_wzr[0], 24 + nt), acc);
    acc = MFMA16(axL0, LFRAG(s_wzr[0], nt), acc);
    acc = MFMA16(axL1, LFRAG(s_wzr[0], 8 + nt), acc);
    acc = MFMA16(ahL0, LFRAG(s_wzr[0], 16 + nt), acc);
    acc = MFMA16(ahL1, LFRAG(s_wzr[0], 24 + nt), acc);
    azr[nt] = acc;
  }
  f32x4 axc[4], ahc[4];
#pragma unroll
  for (int nt = 0; nt < 4; ++nt) {
    f32x4 a = {0.f, 0.f, 0.f, 0.f};
    a = MFMA16(axH0, LFRAG(s_wc[0], nt), a);
    a = MFMA16(axH1, LFRAG(s_wc[0], 4 + nt), a);
    a = MFMA16(axL0, LFRAG(s_wc[0], nt), a);
    a = MFMA16(axL1, LFRAG(s_wc[0], 4 + nt), a);
    axc[nt] = a;
    f32x4 b = {0.f, 0.f, 0.f, 0.f};
    b = MFMA16(ahH0, LFRAG(s_wc[0], 8 + nt), b);
    b = MFMA16(ahH1, LFRAG(s_wc[0], 12 + nt), b);
    b = MFMA16(ahL0, LFRAG(s_wc[0], 8 + nt), b);
    b = MFMA16(ahL1, LFRAG(s_wc[0], 12 + nt), b);
    ahc[nt] = b;
  }
  if (wlo) {
#pragma unroll
    for (int nt = 0; nt < 8; ++nt) {
      azr[nt] = MFMA16(axH0, LFRAG(s_wzr[1], nt), azr[nt]);
      azr[nt] = MFMA16(axH1, LFRAG(s_wzr[1], 8 + nt), azr[nt]);
      azr[nt] = MFMA16(ahH0, LFRAG(s_wzr[1], 16 + nt), azr[nt]);
      azr[nt] = MFMA16(ahH1, LFRAG(s_wzr[1], 24 + nt), azr[nt]);
    }
#pragma unroll
    for (int nt = 0; nt < 4; ++nt) {
      axc[nt] = MFMA16(axH0, LFRAG(s_wc[1], nt), axc[nt]);
      axc[nt] = MFMA16(axH1, LFRAG(s_wc[1], 4 + nt), axc[nt]);
      ahc[nt] = MFMA16(ahH0, LFRAG(s_wc[1], 8 + nt), ahc[nt]);
      ahc[nt] = MFMA16(ahH1, LFRAG(s_wc[1], 12 + nt), ahc[nt]);
    }
  }

#pragma unroll
  for (int tt = 0; tt < 4; ++tt) {
    int col = tt * 16 + l15;
    float bz = s_bias[col], br = s_bias[64 + col], bc = s_bias[128 + col];
#pragma unroll
    for (int r = 0; r < 4; ++r) {
      float z   = sigm(azr[tt][r] + bz);
      float rr  = sigm(azr[4 + tt][r] + br);
      float hcv = ftanh(axc[tt][r] + bc + rr * ahc[tt][r]);
      float hn  = z * h[tt][r] + (1.0f - z) * hcv;
      long row = (long)(l0 + quad * 4 + r) * 128;
      ushort_t hi = f2bf(hn);
      linkHL[row + col] = hi;
      linkHL[row + 64 + col] = f2bf(hn - bf2f(hi));
    }
  }
}

// ---------------------------------------------------------------------------
// Readout: RW=8 waves, direct global fragment reads, no barriers (r7 config).
#define RW 8
__global__ __launch_bounds__(512) void readout_kernel(
    const float* __restrict__ path_state, int n_paths,
    const ushort_t* __restrict__ wr1H, const ushort_t* __restrict__ wr1L,
    const ushort_t* __restrict__ wr2H, const ushort_t* __restrict__ wr2L,
    const float* __restrict__ br1, const float* __restrict__ br2,
    const float* __restrict__ Wf, const float* __restrict__ bfp,
    void* __restrict__ outp, const int* __restrict__ flagp) {
  __shared__ __align__(16) ushort_t s_r1h[RW][16][264];
  __shared__ __align__(16) ushort_t s_r1l[RW][16][264];
  int tid = threadIdx.x;
  int wv = tid >> 6, lane = tid & 63, l15 = lane & 15, quad = lane >> 4;
  int p0 = (blockIdx.x * RW + wv) * 16;
  if (p0 >= n_paths) return;
  int isbf = flagp[0];
  int wlo = (isbf == 0) ? 1 : 0;

  const float* prow = path_state + (long)(p0 + l15) * 64;
  float4 g0 = *(const float4*)(prow + quad * 8);
  float4 g1 = *(const float4*)(prow + quad * 8 + 4);
  float4 g2 = *(const float4*)(prow + 32 + quad * 8);
  float4 g3 = *(const float4*)(prow + 36 + quad * 8);
  bf16x8 axH0, axL0, axH1, axL1;
  split8(g0, g1, axH0, axL0);
  split8(g2, g3, axH1, axL1);

  f32x4 a1[16];
#pragma unroll
  for (int nt = 0; nt < 16; ++nt) {
    f32x4 acc = {0.f, 0.f, 0.f, 0.f};
    acc = MFMA16(axH0, GFRAG(wr1H, nt), acc);
    acc = MFMA16(axH1, GFRAG(wr1H, 16 + nt), acc);
    acc = MFMA16(axL0, GFRAG(wr1H, nt), acc);
    acc = MFMA16(axL1, GFRAG(wr1H, 16 + nt), acc);
    a1[nt] = acc;
  }
  if (wlo) {
#pragma unroll
    for (int nt = 0; nt < 16; ++nt) {
      a1[nt] = MFMA16(axH0, GFRAG(wr1L, nt), a1[nt]);
      a1[nt] = MFMA16(axH1, GFRAG(wr1L, 16 + nt), a1[nt]);
    }
  }
#pragma unroll
  for (int tt = 0; tt < 16; ++tt) {
    float bb = br1[tt * 16 + l15];
#pragma unroll
    for (int r = 0; r < 4; ++r) {
      float v = selu_f(a1[tt][r] + bb);
      ushort_t hi = f2bf(v);
      s_r1h[wv][quad * 4 + r][tt * 16 + l15] = hi;
      s_r1l[wv][quad * 4 + r][tt * 16 + l15] = f2bf(v - bf2f(hi));
    }
  }

  f32x4 a2[16];
  f32x4 zero = {0.f, 0.f, 0.f, 0.f};
#pragma unroll
  for (int nt = 0; nt < 16; ++nt) a2[nt] = zero;
#pragma unroll
  for (int c = 0; c < 8; ++c) {
    bf16x8 afH = *(const bf16x8*)&s_r1h[wv][l15][c * 32 + quad * 8];
    bf16x8 afL = *(const bf16x8*)&s_r1l[wv][l15][c * 32 + quad * 8];
#pragma unroll
    for (int nt = 0; nt < 16; ++nt) {
      a2[nt] = MFMA16(afH, GFRAG(wr2H, c * 16 + nt), a2[nt]);
      a2[nt] = MFMA16(afL, GFRAG(wr2H, c * 16 + nt), a2[nt]);
    }
    if (wlo) {
#pragma unroll
      for (int nt = 0; nt < 16; ++nt)
        a2[nt] = MFMA16(afH, GFRAG(wr2L, c * 16 + nt), a2[nt]);
    }
  }

  float part[4] = {0.f, 0.f, 0.f, 0.f};
#pragma unroll
  for (int tt = 0; tt < 16; ++tt) {
    float wf = Wf[tt * 16 + l15];
    float bb = br2[tt * 16 + l15];
#pragma unroll
    for (int r = 0; r < 4; ++r) part[r] += selu_f(a2[tt][r] + bb) * wf;
  }
  float wfh0 = Wf[256 + l15 * 4 + 0];
  float wfh1 = Wf[256 + l15 * 4 + 1];
  float wfh2 = Wf[256 + l15 * 4 + 2];
  float wfh3 = Wf[256 + l15 * 4 + 3];
#pragma unroll
  for (int r = 0; r < 4; ++r) {
    const float4 hh = *(const float4*)&path_state[(long)(p0 + quad * 4 + r) * 64 + l15 * 4];
    part[r] += hh.x * wfh0 + hh.y * wfh1 + hh.z * wfh2 + hh.w * wfh3;
  }
#pragma unroll
  for (int msk = 1; msk < 16; msk <<= 1)
#pragma unroll
    for (int r = 0; r < 4; ++r) part[r] += __shfl_xor(part[r], msk, 64);
  if (l15 == 0) {
    float bfv = bfp[0];
    if (isbf) {
#pragma unroll
      for (int r = 0; r < 4; ++r) ((ushort_t*)outp)[p0 + quad * 4 + r] = f2bf(part[r] + bfv);
    } else {
#pragma unroll
      for (int r = 0; r < 4; ++r) ((float*)outp)[p0 + quad * 4 + r] = part[r] + bfv;
    }
  }
}

// ---------------------------------------------------------------------------
extern "C" void kernel_launch(void* const* d_in, const int* in_sizes, int n_in,
                              void* d_out, int out_size, void* d_ws, size_t ws_size,
                              hipStream_t stream) {
  const int n_links = in_sizes[0];   // 50000
  const int n_paths = in_sizes[1];   // 100000
  const int E       = in_sizes[2];   // 800000

  char* w = (char*)d_ws;
  size_t off = 0;
  auto take = [&](size_t bytes) { size_t o = off; off += (bytes + 255) & ~(size_t)255; return o; };
  float*    path_state = (float*)(w + take((size_t)n_paths * 64 * 4));
  float*    agg        = (float*)(w + take((size_t)n_links * 64 * 4));
  ushort_t* linkHL     = (ushort_t*)(w + take((size_t)n_links * 128 * 2));
  int*      flag       = (int*)(w + take(256));
  ushort_t* wzrH_p = (ushort_t*)(w + take(32768));
  ushort_t* wzrL_p = (ushort_t*)(w + take(32768));
  ushort_t* wcH_p  = (ushort_t*)(w + take(16384));
  ushort_t* wcL_p  = (ushort_t*)(w + take(16384));
  ushort_t* wzrH_e = (ushort_t*)(w + take(32768));
  ushort_t* wzrL_e = (ushort_t*)(w + take(32768));
  ushort_t* wcH_e  = (ushort_t*)(w + take(16384));
  ushort_t* wcL_e  = (ushort_t*)(w + take(16384));
  ushort_t* wr1H   = (ushort_t*)(w + take(32768));
  ushort_t* wr1L   = (ushort_t*)(w + take(32768));
  ushort_t* wr2H   = (ushort_t*)(w + take(131072));
  ushort_t* wr2L   = (ushort_t*)(w + take(131072));
  float* c_caps    = (float*)(w + take((size_t)in_sizes[0] * 4));
  float* c_traffic = (float*)(w + take((size_t)in_sizes[1] * 4));
  float* c_Wx_p = (float*)(w + take((size_t)in_sizes[5] * 4));
  float* c_Wh_p = (float*)(w + take((size_t)in_sizes[6] * 4));
  float* c_b_p  = (float*)(w + take((size_t)in_sizes[7] * 4));
  float* c_Wx_e = (float*)(w + take((size_t)in_sizes[8] * 4));
  float* c_Wh_e = (float*)(w + take((size_t)in_sizes[9] * 4));
  float* c_b_e  = (float*)(w + take((size_t)in_sizes[10] * 4));
  float* c_Wr1  = (float*)(w + take((size_t)in_sizes[11] * 4));
  float* c_br1  = (float*)(w + take((size_t)in_sizes[12] * 4));
  float* c_Wr2  = (float*)(w + take((size_t)in_sizes[13] * 4));
  float* c_br2  = (float*)(w + take((size_t)in_sizes[14] * 4));
  float* c_Wf   = (float*)(w + take((size_t)in_sizes[15] * 4));
  float* c_bf   = (float*)(w + take((size_t)in_sizes[16] * 4));
  int* cnt    = (int*)(w + take((size_t)n_links * 4));
  int* base   = (int*)(w + take((size_t)n_links * 4));
  int* cursor = (int*)(w + take((size_t)n_links * 4));
  int* pos_of = (int*)(w + take((size_t)E * 4));

  size_t rem = (ws_size > off) ? (ws_size - off) : 0;
  int mmode;
  ushort_t* mH = nullptr;
  if (rem >= (size_t)E * 64 * 2 + 256) { mmode = 1; mH = (ushort_t*)(w + take((size_t)E * 64 * 2)); }
  else mmode = 2;

  detect_dtype<<<1, 64, 0, stream>>>((const uint_t*)d_in[0], flag);

  ConvDesc cd;
  float* dsts[NARR] = {c_caps, c_traffic, c_Wx_p, c_Wh_p, c_b_p, c_Wx_e, c_Wh_e, c_b_e,
                       c_Wr1, c_br1, c_Wr2, c_br2, c_Wf, c_bf};
  int    srcs[NARR] = {0, 1, 5, 6, 7, 8, 9, 10, 11, 12, 13, 14, 15, 16};
  int nblk = 0;
  for (int a = 0; a < NARR; ++a) {
    cd.src[a] = d_in[srcs[a]];
    cd.dst[a] = dsts[a];
    cd.n[a] = in_sizes[srcs[a]];
    cd.blk0[a] = nblk;
    nblk += (cd.n[a] + 255) / 256;
  }
  cd.blk0[NARR] = nblk;
  conv_all<<<nblk, 256, 0, stream>>>(cd, flag);

  {
    long total = (long)(n_links + n_paths) * 64;
    int blocks = (int)((total + 255) / 256);
    init_states<<<blocks, 256, 0, stream>>>(c_caps, c_traffic, linkHL, path_state,
                                            n_links, n_paths);
  }
  {
    PackAll P;
    const float* As[8] = {c_Wx_p, c_Wx_p, c_Wh_p, c_Wx_e, c_Wx_e, c_Wh_e, c_Wr1, c_Wr2};
    const float* Bs[8] = {c_Wh_p, c_Wx_p, c_Wh_p, c_Wh_e, c_Wx_e, c_Wh_e, c_Wr1, c_Wr2};
    ushort_t* dH[8] = {wzrH_p, wcH_p, wcH_p + 4096, wzrH_e, wcH_e, wcH_e + 4096, wr1H, wr2H};
    ushort_t* dL[8] = {wzrL_p, wcL_p, wcL_p + 4096, wzrL_e, wcL_e, wcL_e + 4096, wr1L, wr2L};
    int srcN[8]   = {192, 192, 192, 192, 192, 192, 256, 256};
    int colOff[8] = {0, 128, 128, 0, 128, 128, 0, 0};
    int splitK[8] = {64, 64, 64, 64, 64, 64, 64, 256};
    int nCk[8]    = {4, 2, 2, 4, 2, 2, 2, 8};
    int NT[8]     = {8, 4, 4, 8, 4, 4, 16, 16};
    int pb = 0;
    for (int a = 0; a < 8; ++a) {
      P.A[a] = As[a]; P.B[a] = Bs[a]; P.dH[a] = dH[a]; P.dL[a] = dL[a];
      P.srcN[a] = srcN[a]; P.colOff[a] = colOff[a]; P.splitK[a] = splitK[a];
      P.nCk[a] = nCk[a]; P.NT[a] = NT[a]; P.blk0[a] = pb;
      pb += nCk[a] * NT[a] * 2;
    }
    P.blk0[8] = pb;
    pack_all<<<pb, 256, 0, stream>>>(P);
  }

  const int* links = (const int*)d_in[2];
  if (mmode == 1) {
    (void)hipMemsetAsync(cnt, 0, (size_t)n_links * 4, stream);
    hist_k<<<(E + 255) / 256, 256, 0, stream>>>(links, cnt, E);
    scan_k<<<1, 256, 0, stream>>>(cnt, base, cursor, n_links);
    fill_k<<<(E + 255) / 256, 256, 0, stream>>>(links, cursor, pos_of, E);
  }

  int grid_bf = (n_paths + 16 * PWB - 1) / (16 * PWB);
  int slots   = (n_paths + 16 * PW - 1) / (16 * PW);      // 481
  int gridF   = slots < 256 ? slots : 256;
  int nGroups = (slots + gridF - 1) / gridF;               // 2

  for (int it = 0; it < 3; ++it) {
    int store_m = (it < 2) ? 1 : 0;
    if (mmode == 2 && store_m) (void)hipMemsetAsync(agg, 0, (size_t)n_links * 64 * 4, stream);
    path_kernel_bf16<<<grid_bf, 448, 0, stream>>>(
        links, linkHL, path_state, mH, mmode, store_m, pos_of, agg,
        wzrH_p, wcH_p, c_b_p, flag, n_paths);
    path_kernel_f32<<<gridF, 832, 0, stream>>>(
        links, linkHL, path_state, mH, mmode, store_m, pos_of, agg,
        wzrH_p, wzrL_p, wcH_p, wcL_p, c_b_p, flag, n_paths, nGroups);
    if (it < 2) {
      if (mmode == 1)
        agg_kernel<<<(n_links + 3) / 4, 256, 0, stream>>>(mH, base, cnt, agg, n_links);
      link_kernel<<<n_links / 80, 320, 0, stream>>>(agg, linkHL,
                                                    wzrH_e, wzrL_e, wcH_e, wcL_e, c_b_e, flag);
    }
  }
  readout_kernel<<<(n_paths + 16 * RW - 1) / (16 * RW), 512, 0, stream>>>(
      path_state, n_paths, wr1H, wr1L, wr2H, wr2L,
      c_br1, c_br2, c_Wf, c_bf, d_out, flag);
}

// Round 11
// 1126.065 us; speedup vs baseline: 4.7270x; 4.7270x over previous
//
#include <hip/hip_runtime.h>

typedef unsigned short ushort_t;
typedef unsigned int   uint_t;
typedef short bf16x8 __attribute__((ext_vector_type(8)));
typedef float f32x4  __attribute__((ext_vector_type(4)));

#define MFMA16(a,b,c) __builtin_amdgcn_mfma_f32_16x16x32_bf16((a),(b),(c),0,0,0)

static __device__ __forceinline__ float bf2f(ushort_t b) {
  union { uint_t u; float f; } v; v.u = ((uint_t)b) << 16; return v.f;
}
static __device__ __forceinline__ ushort_t f2bf(float f) {
  union { float f; uint_t u; } v; v.f = f;
  uint_t r = v.u + 0x7fffu + ((v.u >> 16) & 1u);
  return (ushort_t)(r >> 16);
}
static __device__ __forceinline__ float frcp(float x) { return __builtin_amdgcn_rcpf(x); }
static __device__ __forceinline__ float sigm(float x) { return frcp(1.0f + __expf(-x)); }
static __device__ __forceinline__ float ftanh(float x) { return 1.0f - 2.0f * frcp(1.0f + __expf(2.0f * x)); }
static __device__ __forceinline__ float selu_f(float x) {
  float e = 1.6732632423543772f * (__expf(x) - 1.0f);
  return 1.0507009873554805f * (x > 0.0f ? x : e);
}
static __device__ __forceinline__ bf16x8 pack8(float4 a, float4 b) {
  bf16x8 r;
  r[0] = (short)f2bf(a.x); r[1] = (short)f2bf(a.y); r[2] = (short)f2bf(a.z); r[3] = (short)f2bf(a.w);
  r[4] = (short)f2bf(b.x); r[5] = (short)f2bf(b.y); r[6] = (short)f2bf(b.z); r[7] = (short)f2bf(b.w);
  return r;
}
static __device__ __forceinline__ void split8(float4 a, float4 b, bf16x8& hi, bf16x8& lo) {
  hi = pack8(a, b);
  float4 ra, rb;
  ra.x = a.x - bf2f((ushort_t)hi[0]); ra.y = a.y - bf2f((ushort_t)hi[1]);
  ra.z = a.z - bf2f((ushort_t)hi[2]); ra.w = a.w - bf2f((ushort_t)hi[3]);
  rb.x = b.x - bf2f((ushort_t)hi[4]); rb.y = b.y - bf2f((ushort_t)hi[5]);
  rb.z = b.z - bf2f((ushort_t)hi[6]); rb.w = b.w - bf2f((ushort_t)hi[7]);
  lo = pack8(ra, rb);
}

#define GFRAG(ptr, f) (*(const bf16x8*)&(ptr)[(((f) * 64 + lane)) * 8])
#define LFRAG(arr, f) (*(const bf16x8*)&(arr)[(((f) * 64 + lane)) * 8])

// ---------------------------------------------------------------------------
__global__ void detect_dtype(const uint_t* __restrict__ caps, int* __restrict__ flag) {
  int lane = threadIdx.x;
  uint_t d = caps[lane];
  uint_t lo = d & 0xFFFFu, hi = d >> 16;
  bool isbf = (lo >= 0x3F00u && lo <= 0x3FC0u) && (hi >= 0x3F00u && hi <= 0x3FC0u);
  unsigned long long m = __ballot(isbf);
  if (lane == 0) *flag = (__popcll(m) >= 48) ? 1 : 0;
}

// ---------------------------------------------------------------------------
#define NARR 14
struct ConvDesc {
  const void* src[NARR];
  float*      dst[NARR];
  int         n[NARR];
  int         blk0[NARR + 1];
};
__global__ void conv_all(ConvDesc d, const int* __restrict__ flag) {
  int isbf = *flag;
  int b = blockIdx.x;
  int a = 0;
  while (a + 1 < NARR && b >= d.blk0[a + 1]) ++a;
  int idx = (b - d.blk0[a]) * 256 + threadIdx.x;
  if (idx >= d.n[a]) return;
  d.dst[a][idx] = isbf ? bf2f(((const ushort_t*)d.src[a])[idx])
                       : ((const float*)d.src[a])[idx];
}

// ---------------------------------------------------------------------------
struct PackAll {
  const float* A[8];
  const float* B[8];
  ushort_t* dH[8];
  ushort_t* dL[8];
  int srcN[8], colOff[8], splitK[8], nCk[8], NT[8], blk0[9];
};
__global__ void pack_all(PackAll P) {
  int b = blockIdx.x;
  int a = 0;
  while (a + 1 < 8 && b >= P.blk0[a + 1]) ++a;
  int i = (b - P.blk0[a]) * 256 + threadIdx.x;
  int j = i & 7;
  int lane = (i >> 3) & 63;
  int f = i >> 9;
  int c = f / P.NT[a], nt = f - c * P.NT[a];
  int k = c * 32 + ((lane >> 4) << 3) + j;
  int n = P.colOff[a] + nt * 16 + (lane & 15);
  float v = (k < P.splitK[a]) ? P.A[a][k * P.srcN[a] + n]
                              : P.B[a][(k - P.splitK[a]) * P.srcN[a] + n];
  ushort_t hi = f2bf(v);
  P.dH[a][i] = hi;
  P.dL[a][i] = f2bf(v - bf2f(hi));
}

// ---------------------------------------------------------------------------
__global__ void init_states(const float* __restrict__ caps, const float* __restrict__ traffic,
                            ushort_t* __restrict__ linkHL,
                            float* __restrict__ path_state, int n_links, int n_paths) {
  long i = (long)blockIdx.x * 256 + threadIdx.x;
  long total = (long)(n_links + n_paths) * 64;
  if (i >= total) return;
  int row = (int)(i >> 6), col = (int)(i & 63);
  if (row < n_links) {
    float v = (col == 0) ? caps[row] : 0.0f;
    ushort_t hi = f2bf(v);
    linkHL[(long)row * 128 + col] = hi;
    linkHL[(long)row * 128 + 64 + col] = f2bf(v - bf2f(hi));
  } else {
    int pr = row - n_links;
    path_state[(long)pr * 64 + col] = (col == 0) ? traffic[pr] : 0.0f;
  }
}

// ---------------------------------------------------------------------------
__global__ void hist_k(const int* __restrict__ links, int* __restrict__ cnt, int E) {
  int e = blockIdx.x * 256 + threadIdx.x;
  if (e < E) atomicAdd(&cnt[links[e]], 1);
}
__global__ void scan_k(const int* __restrict__ cnt, int* __restrict__ base,
                       int* __restrict__ cursor, int n) {
  __shared__ int part[256];
  int tid = threadIdx.x;
  int chunk = (n + 255) / 256;
  int lo = tid * chunk, hiEnd = lo + chunk; if (hiEnd > n) hiEnd = n;
  int s = 0;
  for (int i = lo; i < hiEnd; ++i) s += cnt[i];
  part[tid] = s;
  __syncthreads();
  if (tid == 0) { int acc = 0; for (int i = 0; i < 256; ++i) { int v = part[i]; part[i] = acc; acc += v; } }
  __syncthreads();
  int acc = part[tid];
  for (int i = lo; i < hiEnd; ++i) { base[i] = acc; cursor[i] = acc; acc += cnt[i]; }
}
__global__ void fill_k(const int* __restrict__ links, int* __restrict__ cursor,
                       int* __restrict__ pos_of, int E) {
  int e = blockIdx.x * 256 + threadIdx.x;
  if (e >= E) return;
  pos_of[e] = atomicAdd(&cursor[links[e]], 1);
}

// ---------------------------------------------------------------------------
// Aggregate bf16 m (CSR-ordered, contiguous per link) -> fp32 agg.
// 2-way unroll with independent accumulators to pipeline the loads.
__global__ __launch_bounds__(256) void agg_kernel(
    const ushort_t* __restrict__ mH,
    const int* __restrict__ base, const int* __restrict__ cnt,
    float* __restrict__ agg, int n_links) {
  int l = blockIdx.x * 4 + (threadIdx.x >> 6);
  if (l >= n_links) return;
  int lane = threadIdx.x & 63;
  int s = base[l], d = cnt[l];
  float acc0 = 0.0f, acc1 = 0.0f;
  int i = 0;
  for (; i + 2 <= d; i += 2) {
    acc0 += bf2f(mH[(long)(s + i) * 64 + lane]);
    acc1 += bf2f(mH[(long)(s + i + 1) * 64 + lane]);
  }
  if (i < d) acc0 += bf2f(mH[(long)(s + i) * 64 + lane]);
  agg[(long)l * 64 + lane] = acc0 + acc1;
}

// ---------------------------------------------------------------------------
// Path GRU, bf16-dataset variant (flag==1). Dormant for fp32 datasets.
#define PWB 7
__global__ __launch_bounds__(448) void path_kernel_bf16(
    const int* __restrict__ links,
    const ushort_t* __restrict__ linkHL,
    float* __restrict__ path_state,
    ushort_t* __restrict__ mH, int mmode, int store_m,
    const int* __restrict__ pos_of, float* __restrict__ agg,
    const ushort_t* __restrict__ wzrH, const ushort_t* __restrict__ wcH,
    const float* __restrict__ bp, const int* __restrict__ flagp, int n_paths) {
  __shared__ __align__(16) ushort_t s_wzr[32 * 512];
  __shared__ __align__(16) ushort_t s_wc[16 * 512];
  __shared__ __align__(16) ushort_t s_hh[PWB][16][68];
  __shared__ __align__(16) ushort_t s_hl[PWB][16][68];
  __shared__ float s_bias[192];

  if (flagp[0] == 0) return;

  int tid = threadIdx.x;
  {
    uint_t* s0 = (uint_t*)s_wzr; const uint_t* g0 = (const uint_t*)wzrH;
    for (int i = tid; i < 8192; i += 448) s0[i] = g0[i];
    uint_t* s1 = (uint_t*)s_wc;  const uint_t* g1 = (const uint_t*)wcH;
    for (int i = tid; i < 4096; i += 448) s1[i] = g1[i];
    for (int i = tid; i < 192; i += 448) s_bias[i] = bp[i];
  }

  int wv = tid >> 6, lane = tid & 63, l15 = lane & 15, quad = lane >> 4;
  int p0 = (blockIdx.x * PWB + wv) * 16;
  bool valid = (p0 < n_paths);

  float h[4][4];
  if (valid) {
#pragma unroll
    for (int tt = 0; tt < 4; ++tt)
#pragma unroll
      for (int r = 0; r < 4; ++r) {
        float v = path_state[(long)(p0 + quad * 4 + r) * 64 + tt * 16 + l15];
        h[tt][r] = v;
        ushort_t hi = f2bf(v);
        s_hh[wv][quad * 4 + r][tt * 16 + l15] = hi;
        s_hl[wv][quad * 4 + r][tt * 16 + l15] = f2bf(v - bf2f(hi));
      }
  }
  __syncthreads();
  if (!valid) return;

  for (int t = 0; t < 8; ++t) {
    int la = links[(p0 + l15) * 8 + t];
    const ushort_t* xr = linkHL + (long)la * 128;
    bf16x8 axH0 = *(const bf16x8*)(xr + quad * 8);
    bf16x8 axH1 = *(const bf16x8*)(xr + 32 + quad * 8);
    bf16x8 axL0 = *(const bf16x8*)(xr + 64 + quad * 8);
    bf16x8 axL1 = *(const bf16x8*)(xr + 96 + quad * 8);
    bf16x8 ahH0 = *(const bf16x8*)&s_hh[wv][l15][quad * 8];
    bf16x8 ahH1 = *(const bf16x8*)&s_hh[wv][l15][32 + quad * 8];
    bf16x8 ahL0 = *(const bf16x8*)&s_hl[wv][l15][quad * 8];
    bf16x8 ahL1 = *(const bf16x8*)&s_hl[wv][l15][32 + quad * 8];

    f32x4 azr[8];
#pragma unroll
    for (int nt = 0; nt < 8; ++nt) {
      f32x4 acc = {0.f, 0.f, 0.f, 0.f};
      acc = MFMA16(axH0, LFRAG(s_wzr, nt), acc);
      acc = MFMA16(axH1, LFRAG(s_wzr, 8 + nt), acc);
      acc = MFMA16(ahH0, LFRAG(s_wzr, 16 + nt), acc);
      acc = MFMA16(ahH1, LFRAG(s_wzr, 24 + nt), acc);
      acc = MFMA16(axL0, LFRAG(s_wzr, nt), acc);
      acc = MFMA16(axL1, LFRAG(s_wzr, 8 + nt), acc);
      acc = MFMA16(ahL0, LFRAG(s_wzr, 16 + nt), acc);
      acc = MFMA16(ahL1, LFRAG(s_wzr, 24 + nt), acc);
      azr[nt] = acc;
    }
    f32x4 axc[4], ahc[4];
#pragma unroll
    for (int nt = 0; nt < 4; ++nt) {
      f32x4 a = {0.f, 0.f, 0.f, 0.f};
      a = MFMA16(axH0, LFRAG(s_wc, nt), a);
      a = MFMA16(axH1, LFRAG(s_wc, 4 + nt), a);
      a = MFMA16(axL0, LFRAG(s_wc, nt), a);
      a = MFMA16(axL1, LFRAG(s_wc, 4 + nt), a);
      axc[nt] = a;
      f32x4 b = {0.f, 0.f, 0.f, 0.f};
      b = MFMA16(ahH0, LFRAG(s_wc, 8 + nt), b);
      b = MFMA16(ahH1, LFRAG(s_wc, 12 + nt), b);
      b = MFMA16(ahL0, LFRAG(s_wc, 8 + nt), b);
      b = MFMA16(ahL1, LFRAG(s_wc, 12 + nt), b);
      ahc[nt] = b;
    }

    int pr[4] = {0, 0, 0, 0};
    if (store_m) {
      if (mmode == 2) {
#pragma unroll
        for (int r = 0; r < 4; ++r) pr[r] = links[(p0 + quad * 4 + r) * 8 + t];
      } else {
#pragma unroll
        for (int r = 0; r < 4; ++r) pr[r] = pos_of[(p0 + quad * 4 + r) * 8 + t];
      }
    }

#pragma unroll
    for (int tt = 0; tt < 4; ++tt) {
      int col = tt * 16 + l15;
      float bz = s_bias[col], br = s_bias[64 + col], bc = s_bias[128 + col];
#pragma unroll
      for (int r = 0; r < 4; ++r) {
        float z   = sigm(azr[tt][r] + bz);
        float rr  = sigm(azr[4 + tt][r] + br);
        float hcv = ftanh(axc[tt][r] + bc + rr * ahc[tt][r]);
        float hn  = z * h[tt][r] + (1.0f - z) * hcv;
        h[tt][r] = hn;
        if (store_m) {
          if (mmode == 1) mH[(long)pr[r] * 64 + col] = f2bf(hn);
          else atomicAdd(&agg[(long)pr[r] * 64 + col], hn);
        }
        ushort_t hi = f2bf(hn);
        s_hh[wv][quad * 4 + r][col] = hi;
        s_hl[wv][quad * 4 + r][col] = f2bf(hn - bf2f(hi));
      }
    }
  }

#pragma unroll
  for (int tt = 0; tt < 4; ++tt)
#pragma unroll
    for (int r = 0; r < 4; ++r)
      path_state[(long)(p0 + quad * 4 + r) * 64 + tt * 16 + l15] = h[tt][r];
}

// ---------------------------------------------------------------------------
// Path GRU, fp32-dataset variant: 13 waves (832 thr, 159 KB LDS), grid-stride
// groups amortize the 96 KB weight staging; x-frag gathers prefetched 1 step.
// m stored bf16 at CSR slot (r7/r9 config: best measured total, 1131 us).
#define PW 13
__global__ __launch_bounds__(832) void path_kernel_f32(
    const int* __restrict__ links,
    const ushort_t* __restrict__ linkHL,
    float* __restrict__ path_state,
    ushort_t* __restrict__ mH, int mmode, int store_m,
    const int* __restrict__ pos_of, float* __restrict__ agg,
    const ushort_t* __restrict__ wzrH, const ushort_t* __restrict__ wzrL,
    const ushort_t* __restrict__ wcH,  const ushort_t* __restrict__ wcL,
    const float* __restrict__ bp, const int* __restrict__ flagp,
    int n_paths, int nGroups) {
  __shared__ __align__(16) ushort_t s_wzr[2][32 * 512];
  __shared__ __align__(16) ushort_t s_wc[2][16 * 512];
  __shared__ __align__(16) ushort_t s_hh[PW][16][72];
  __shared__ __align__(16) ushort_t s_hl[PW][16][72];
  __shared__ float s_bias[192];

  if (flagp[0] != 0) return;

  int tid = threadIdx.x;
  {
    uint_t* s0 = (uint_t*)s_wzr[0]; const uint_t* g0 = (const uint_t*)wzrH;
    for (int i = tid; i < 8192; i += 832) s0[i] = g0[i];
    uint_t* s1 = (uint_t*)s_wc[0];  const uint_t* g1 = (const uint_t*)wcH;
    for (int i = tid; i < 4096; i += 832) s1[i] = g1[i];
    uint_t* s2 = (uint_t*)s_wzr[1]; const uint_t* g2 = (const uint_t*)wzrL;
    for (int i = tid; i < 8192; i += 832) s2[i] = g2[i];
    uint_t* s3 = (uint_t*)s_wc[1];  const uint_t* g3 = (const uint_t*)wcL;
    for (int i = tid; i < 4096; i += 832) s3[i] = g3[i];
    for (int i = tid; i < 192; i += 832) s_bias[i] = bp[i];
  }
  __syncthreads();

  int wv = tid >> 6, lane = tid & 63, l15 = lane & 15, quad = lane >> 4;

  for (int g = 0; g < nGroups; ++g) {
    int slot = g * gridDim.x + blockIdx.x;
    int p0 = (slot * PW + wv) * 16;
    if (p0 >= n_paths) continue;

    float h[4][4];
#pragma unroll
    for (int tt = 0; tt < 4; ++tt)
#pragma unroll
      for (int r = 0; r < 4; ++r) {
        float v = path_state[(long)(p0 + quad * 4 + r) * 64 + tt * 16 + l15];
        h[tt][r] = v;
        ushort_t hi = f2bf(v);
        s_hh[wv][quad * 4 + r][tt * 16 + l15] = hi;
        s_hl[wv][quad * 4 + r][tt * 16 + l15] = f2bf(v - bf2f(hi));
      }

    const int* lrow = links + (long)(p0 + l15) * 8;
    {
      int la0 = lrow[0];
      const ushort_t* x0 = linkHL + (long)la0 * 128;
      bf16x8 nH0 = *(const bf16x8*)(x0 + quad * 8);
      bf16x8 nH1 = *(const bf16x8*)(x0 + 32 + quad * 8);
      bf16x8 nL0 = *(const bf16x8*)(x0 + 64 + quad * 8);
      bf16x8 nL1 = *(const bf16x8*)(x0 + 96 + quad * 8);

      for (int t = 0; t < 8; ++t) {
        bf16x8 axH0 = nH0, axH1 = nH1, axL0 = nL0, axL1 = nL1;
        if (t < 7) {
          int la2 = lrow[t + 1];
          const ushort_t* x2 = linkHL + (long)la2 * 128;
          nH0 = *(const bf16x8*)(x2 + quad * 8);
          nH1 = *(const bf16x8*)(x2 + 32 + quad * 8);
          nL0 = *(const bf16x8*)(x2 + 64 + quad * 8);
          nL1 = *(const bf16x8*)(x2 + 96 + quad * 8);
        }
        int pr[4] = {0, 0, 0, 0};
        if (store_m) {
          if (mmode == 2) {
#pragma unroll
            for (int r = 0; r < 4; ++r) pr[r] = links[(long)(p0 + quad * 4 + r) * 8 + t];
          } else {
#pragma unroll
            for (int r = 0; r < 4; ++r) pr[r] = pos_of[(long)(p0 + quad * 4 + r) * 8 + t];
          }
        }
        bf16x8 ahH0 = *(const bf16x8*)&s_hh[wv][l15][quad * 8];
        bf16x8 ahH1 = *(const bf16x8*)&s_hh[wv][l15][32 + quad * 8];
        bf16x8 ahL0 = *(const bf16x8*)&s_hl[wv][l15][quad * 8];
        bf16x8 ahL1 = *(const bf16x8*)&s_hl[wv][l15][32 + quad * 8];

        f32x4 azr[8];
#pragma unroll
        for (int nt = 0; nt < 8; ++nt) {
          f32x4 acc = {0.f, 0.f, 0.f, 0.f};
          acc = MFMA16(axH0, LFRAG(s_wzr[0], nt), acc);
          acc = MFMA16(axH1, LFRAG(s_wzr[0], 8 + nt), acc);
          acc = MFMA16(axL0, LFRAG(s_wzr[0], nt), acc);
          acc = MFMA16(axL1, LFRAG(s_wzr[0], 8 + nt), acc);
          acc = MFMA16(axH0, LFRAG(s_wzr[1], nt), acc);
          acc = MFMA16(axH1, LFRAG(s_wzr[1], 8 + nt), acc);
          acc = MFMA16(ahH0, LFRAG(s_wzr[0], 16 + nt), acc);
          acc = MFMA16(ahH1, LFRAG(s_wzr[0], 24 + nt), acc);
          acc = MFMA16(ahL0, LFRAG(s_wzr[0], 16 + nt), acc);
          acc = MFMA16(ahL1, LFRAG(s_wzr[0], 24 + nt), acc);
          acc = MFMA16(ahH0, LFRAG(s_wzr[1], 16 + nt), acc);
          acc = MFMA16(ahH1, LFRAG(s_wzr[1], 24 + nt), acc);
          azr[nt] = acc;
        }
        f32x4 axc[4], ahc[4];
#pragma unroll
        for (int nt = 0; nt < 4; ++nt) {
          f32x4 a = {0.f, 0.f, 0.f, 0.f};
          a = MFMA16(axH0, LFRAG(s_wc[0], nt), a);
          a = MFMA16(axH1, LFRAG(s_wc[0], 4 + nt), a);
          a = MFMA16(axL0, LFRAG(s_wc[0], nt), a);
          a = MFMA16(axL1, LFRAG(s_wc[0], 4 + nt), a);
          a = MFMA16(axH0, LFRAG(s_wc[1], nt), a);
          a = MFMA16(axH1, LFRAG(s_wc[1], 4 + nt), a);
          axc[nt] = a;
          f32x4 b = {0.f, 0.f, 0.f, 0.f};
          b = MFMA16(ahH0, LFRAG(s_wc[0], 8 + nt), b);
          b = MFMA16(ahH1, LFRAG(s_wc[0], 12 + nt), b);
          b = MFMA16(ahL0, LFRAG(s_wc[0], 8 + nt), b);
          b = MFMA16(ahL1, LFRAG(s_wc[0], 12 + nt), b);
          b = MFMA16(ahH0, LFRAG(s_wc[1], 8 + nt), b);
          b = MFMA16(ahH1, LFRAG(s_wc[1], 12 + nt), b);
          ahc[nt] = b;
        }

#pragma unroll
        for (int tt = 0; tt < 4; ++tt) {
          int col = tt * 16 + l15;
          float bz = s_bias[col], br = s_bias[64 + col], bc = s_bias[128 + col];
#pragma unroll
          for (int r = 0; r < 4; ++r) {
            float z   = sigm(azr[tt][r] + bz);
            float rr  = sigm(azr[4 + tt][r] + br);
            float hcv = ftanh(axc[tt][r] + bc + rr * ahc[tt][r]);
            float hn  = z * h[tt][r] + (1.0f - z) * hcv;
            h[tt][r] = hn;
            if (store_m) {
              if (mmode == 1) mH[(long)pr[r] * 64 + col] = f2bf(hn);
              else atomicAdd(&agg[(long)pr[r] * 64 + col], hn);
            }
            ushort_t hi = f2bf(hn);
            s_hh[wv][quad * 4 + r][col] = hi;
            s_hl[wv][quad * 4 + r][col] = f2bf(hn - bf2f(hi));
          }
        }
      }
    }

#pragma unroll
    for (int tt = 0; tt < 4; ++tt)
#pragma unroll
      for (int r = 0; r < 4; ++r)
        path_state[(long)(p0 + quad * 4 + r) * 64 + tt * 16 + l15] = h[tt][r];
  }
}

// ---------------------------------------------------------------------------
__global__ __launch_bounds__(320) void link_kernel(
    const float* __restrict__ agg,
    ushort_t* __restrict__ linkHL,
    const ushort_t* __restrict__ wzrH, const ushort_t* __restrict__ wzrL,
    const ushort_t* __restrict__ wcH,  const ushort_t* __restrict__ wcL,
    const float* __restrict__ be, const int* __restrict__ flagp) {
  __shared__ __align__(16) ushort_t s_wzr[2][32 * 512];
  __shared__ __align__(16) ushort_t s_wc[2][16 * 512];
  __shared__ float s_bias[192];

  int tid = threadIdx.x;
  int wlo = (flagp[0] == 0) ? 1 : 0;
  {
    uint_t* s0 = (uint_t*)s_wzr[0]; const uint_t* g0 = (const uint_t*)wzrH;
    for (int i = tid; i < 8192; i += 320) s0[i] = g0[i];
    uint_t* s1 = (uint_t*)s_wc[0];  const uint_t* g1 = (const uint_t*)wcH;
    for (int i = tid; i < 4096; i += 320) s1[i] = g1[i];
    if (wlo) {
      uint_t* s2 = (uint_t*)s_wzr[1]; const uint_t* g2 = (const uint_t*)wzrL;
      for (int i = tid; i < 8192; i += 320) s2[i] = g2[i];
      uint_t* s3 = (uint_t*)s_wc[1];  const uint_t* g3 = (const uint_t*)wcL;
      for (int i = tid; i < 4096; i += 320) s3[i] = g3[i];
    }
    for (int i = tid; i < 192; i += 320) s_bias[i] = be[i];
  }
  __syncthreads();

  int wv = tid >> 6, lane = tid & 63, l15 = lane & 15, quad = lane >> 4;
  int l0 = (blockIdx.x * 5 + wv) * 16;

  const float* arow = agg + (long)(l0 + l15) * 64;
  float4 f0 = *(const float4*)(arow + quad * 8);
  float4 f1 = *(const float4*)(arow + quad * 8 + 4);
  float4 f2 = *(const float4*)(arow + 32 + quad * 8);
  float4 f3 = *(const float4*)(arow + 36 + quad * 8);
  bf16x8 axH0, axL0, axH1, axL1;
  split8(f0, f1, axH0, axL0);
  split8(f2, f3, axH1, axL1);
  const ushort_t* hr = linkHL + (long)(l0 + l15) * 128;
  bf16x8 ahH0 = *(const bf16x8*)(hr + quad * 8);
  bf16x8 ahH1 = *(const bf16x8*)(hr + 32 + quad * 8);
  bf16x8 ahL0 = *(const bf16x8*)(hr + 64 + quad * 8);
  bf16x8 ahL1 = *(const bf16x8*)(hr + 96 + quad * 8);

  float h[4][4];
#pragma unroll
  for (int tt = 0; tt < 4; ++tt)
#pragma unroll
    for (int r = 0; r < 4; ++r) {
      long row = (long)(l0 + quad * 4 + r) * 128;
      int col = tt * 16 + l15;
      h[tt][r] = bf2f(linkHL[row + col]) + bf2f(linkHL[row + 64 + col]);
    }

  f32x4 azr[8];
#pragma unroll
  for (int nt = 0; nt < 8; ++nt) {
    f32x4 acc = {0.f, 0.f, 0.f, 0.f};
    acc = MFMA16(axH0, LFRAG(s_wzr[0], nt), acc);
    acc = MFMA16(axH1, LFRAG(s_wzr[0], 8 + nt), acc);
    acc = MFMA16(ahH0, LFRAG(s_wzr[0], 16 + nt), acc);
    acc = MFMA16(ahH1, LFRAG(s_wzr[0], 24 + nt), acc);
    acc = MFMA16(axL0, LFRAG(s_wzr[0], nt), acc);
    acc = MFMA16(axL1, LFRAG(s_wzr[0], 8 + nt), acc);
    acc = MFMA16(ahL0, LFRAG(s_wzr[0], 16 + nt), acc);
    acc = MFMA16(ahL1, LFRAG(s_wzr[0], 24 + nt), acc);
    azr[nt] = acc;
  }
  f32x4 axc[4], ahc[4];
#pragma unroll
  for (int nt = 0; nt < 4; ++nt) {
    f32x4 a = {0.f, 0.f, 0.f, 0.f};
    a = MFMA16(axH0, LFRAG(s_wc[0], nt), a);
    a = MFMA16(axH1, LFRAG(s_wc[0], 4 + nt), a);
    a = MFMA16(axL0, LFRAG(s_wc[0], nt), a);
    a = MFMA16(axL1, LFRAG(s_wc[0], 4 + nt), a);
    axc[nt] = a;
    f32x4 b = {0.f, 0.f, 0.f, 0.f};
    b = MFMA16(ahH0, LFRAG(s_wc[0], 8 + nt), b);
    b = MFMA16(ahH1, LFRAG(s_wc[0], 12 + nt), b);
    b = MFMA16(ahL0, LFRAG(s_wc[0], 8 + nt), b);
    b = MFMA16(ahL1, LFRAG(s_wc[0], 12 + nt), b);
    ahc[nt] = b;
  }
  if (wlo) {
#pragma unroll
    for (int nt = 0; nt < 8; ++nt) {
      azr[nt] = MFMA16(axH0, LFRAG(s_wzr[1], nt), azr[nt]);
      azr[nt] = MFMA16(axH1, LFRAG(s_wzr[1], 8 + nt), azr[nt]);
      azr[nt] = MFMA16(ahH0, LFRAG(s_wzr[1], 16 + nt), azr[nt]);
      azr[nt] = MFMA16(ahH1, LFRAG(s_wzr[1], 24 + nt), azr[nt]);
    }
#pragma unroll
    for (int nt = 0; nt < 4; ++nt) {
      axc[nt] = MFMA16(axH0, LFRAG(s_wc[1], nt), axc[nt]);
      axc[nt] = MFMA16(axH1, LFRAG(s_wc[1], 4 + nt), axc[nt]);
      ahc[nt] = MFMA16(ahH0, LFRAG(s_wc[1], 8 + nt), ahc[nt]);
      ahc[nt] = MFMA16(ahH1, LFRAG(s_wc[1], 12 + nt), ahc[nt]);
    }
  }

#pragma unroll
  for (int tt = 0; tt < 4; ++tt) {
    int col = tt * 16 + l15;
    float bz = s_bias[col], br = s_bias[64 + col], bc = s_bias[128 + col];
#pragma unroll
    for (int r = 0; r < 4; ++r) {
      float z   = sigm(azr[tt][r] + bz);
      float rr  = sigm(azr[4 + tt][r] + br);
      float hcv = ftanh(axc[tt][r] + bc + rr * ahc[tt][r]);
      float hn  = z * h[tt][r] + (1.0f - z) * hcv;
      long row = (long)(l0 + quad * 4 + r) * 128;
      ushort_t hi = f2bf(hn);
      linkHL[row + col] = hi;
      linkHL[row + 64 + col] = f2bf(hn - bf2f(hi));
    }
  }
}

// ---------------------------------------------------------------------------
// Readout: RW=8 waves, direct global fragment reads, no barriers (r7 config).
#define RW 8
__global__ __launch_bounds__(512) void readout_kernel(
    const float* __restrict__ path_state, int n_paths,
    const ushort_t* __restrict__ wr1H, const ushort_t* __restrict__ wr1L,
    const ushort_t* __restrict__ wr2H, const ushort_t* __restrict__ wr2L,
    const float* __restrict__ br1, const float* __restrict__ br2,
    const float* __restrict__ Wf, const float* __restrict__ bfp,
    void* __restrict__ outp, const int* __restrict__ flagp) {
  __shared__ __align__(16) ushort_t s_r1h[RW][16][264];
  __shared__ __align__(16) ushort_t s_r1l[RW][16][264];
  int tid = threadIdx.x;
  int wv = tid >> 6, lane = tid & 63, l15 = lane & 15, quad = lane >> 4;
  int p0 = (blockIdx.x * RW + wv) * 16;
  if (p0 >= n_paths) return;
  int isbf = flagp[0];
  int wlo = (isbf == 0) ? 1 : 0;

  const float* prow = path_state + (long)(p0 + l15) * 64;
  float4 g0 = *(const float4*)(prow + quad * 8);
  float4 g1 = *(const float4*)(prow + quad * 8 + 4);
  float4 g2 = *(const float4*)(prow + 32 + quad * 8);
  float4 g3 = *(const float4*)(prow + 36 + quad * 8);
  bf16x8 axH0, axL0, axH1, axL1;
  split8(g0, g1, axH0, axL0);
  split8(g2, g3, axH1, axL1);

  f32x4 a1[16];
#pragma unroll
  for (int nt = 0; nt < 16; ++nt) {
    f32x4 acc = {0.f, 0.f, 0.f, 0.f};
    acc = MFMA16(axH0, GFRAG(wr1H, nt), acc);
    acc = MFMA16(axH1, GFRAG(wr1H, 16 + nt), acc);
    acc = MFMA16(axL0, GFRAG(wr1H, nt), acc);
    acc = MFMA16(axL1, GFRAG(wr1H, 16 + nt), acc);
    a1[nt] = acc;
  }
  if (wlo) {
#pragma unroll
    for (int nt = 0; nt < 16; ++nt) {
      a1[nt] = MFMA16(axH0, GFRAG(wr1L, nt), a1[nt]);
      a1[nt] = MFMA16(axH1, GFRAG(wr1L, 16 + nt), a1[nt]);
    }
  }
#pragma unroll
  for (int tt = 0; tt < 16; ++tt) {
    float bb = br1[tt * 16 + l15];
#pragma unroll
    for (int r = 0; r < 4; ++r) {
      float v = selu_f(a1[tt][r] + bb);
      ushort_t hi = f2bf(v);
      s_r1h[wv][quad * 4 + r][tt * 16 + l15] = hi;
      s_r1l[wv][quad * 4 + r][tt * 16 + l15] = f2bf(v - bf2f(hi));
    }
  }

  f32x4 a2[16];
  f32x4 zero = {0.f, 0.f, 0.f, 0.f};
#pragma unroll
  for (int nt = 0; nt < 16; ++nt) a2[nt] = zero;
#pragma unroll
  for (int c = 0; c < 8; ++c) {
    bf16x8 afH = *(const bf16x8*)&s_r1h[wv][l15][c * 32 + quad * 8];
    bf16x8 afL = *(const bf16x8*)&s_r1l[wv][l15][c * 32 + quad * 8];
#pragma unroll
    for (int nt = 0; nt < 16; ++nt) {
      a2[nt] = MFMA16(afH, GFRAG(wr2H, c * 16 + nt), a2[nt]);
      a2[nt] = MFMA16(afL, GFRAG(wr2H, c * 16 + nt), a2[nt]);
    }
    if (wlo) {
#pragma unroll
      for (int nt = 0; nt < 16; ++nt)
        a2[nt] = MFMA16(afH, GFRAG(wr2L, c * 16 + nt), a2[nt]);
    }
  }

  float part[4] = {0.f, 0.f, 0.f, 0.f};
#pragma unroll
  for (int tt = 0; tt < 16; ++tt) {
    float wf = Wf[tt * 16 + l15];
    float bb = br2[tt * 16 + l15];
#pragma unroll
    for (int r = 0; r < 4; ++r) part[r] += selu_f(a2[tt][r] + bb) * wf;
  }
  float wfh0 = Wf[256 + l15 * 4 + 0];
  float wfh1 = Wf[256 + l15 * 4 + 1];
  float wfh2 = Wf[256 + l15 * 4 + 2];
  float wfh3 = Wf[256 + l15 * 4 + 3];
#pragma unroll
  for (int r = 0; r < 4; ++r) {
    const float4 hh = *(const float4*)&path_state[(long)(p0 + quad * 4 + r) * 64 + l15 * 4];
    part[r] += hh.x * wfh0 + hh.y * wfh1 + hh.z * wfh2 + hh.w * wfh3;
  }
#pragma unroll
  for (int msk = 1; msk < 16; msk <<= 1)
#pragma unroll
    for (int r = 0; r < 4; ++r) part[r] += __shfl_xor(part[r], msk, 64);
  if (l15 == 0) {
    float bfv = bfp[0];
    if (isbf) {
#pragma unroll
      for (int r = 0; r < 4; ++r) ((ushort_t*)outp)[p0 + quad * 4 + r] = f2bf(part[r] + bfv);
    } else {
#pragma unroll
      for (int r = 0; r < 4; ++r) ((float*)outp)[p0 + quad * 4 + r] = part[r] + bfv;
    }
  }
}

// ---------------------------------------------------------------------------
extern "C" void kernel_launch(void* const* d_in, const int* in_sizes, int n_in,
                              void* d_out, int out_size, void* d_ws, size_t ws_size,
                              hipStream_t stream) {
  const int n_links = in_sizes[0];   // 50000
  const int n_paths = in_sizes[1];   // 100000
  const int E       = in_sizes[2];   // 800000

  char* w = (char*)d_ws;
  size_t off = 0;
  auto take = [&](size_t bytes) { size_t o = off; off += (bytes + 255) & ~(size_t)255; return o; };
  float*    path_state = (float*)(w + take((size_t)n_paths * 64 * 4));
  float*    agg        = (float*)(w + take((size_t)n_links * 64 * 4));
  ushort_t* linkHL     = (ushort_t*)(w + take((size_t)n_links * 128 * 2));
  int*      flag       = (int*)(w + take(256));
  ushort_t* wzrH_p = (ushort_t*)(w + take(32768));
  ushort_t* wzrL_p = (ushort_t*)(w + take(32768));
  ushort_t* wcH_p  = (ushort_t*)(w + take(16384));
  ushort_t* wcL_p  = (ushort_t*)(w + take(16384));
  ushort_t* wzrH_e = (ushort_t*)(w + take(32768));
  ushort_t* wzrL_e = (ushort_t*)(w + take(32768));
  ushort_t* wcH_e  = (ushort_t*)(w + take(16384));
  ushort_t* wcL_e  = (ushort_t*)(w + take(16384));
  ushort_t* wr1H   = (ushort_t*)(w + take(32768));
  ushort_t* wr1L   = (ushort_t*)(w + take(32768));
  ushort_t* wr2H   = (ushort_t*)(w + take(131072));
  ushort_t* wr2L   = (ushort_t*)(w + take(131072));
  float* c_caps    = (float*)(w + take((size_t)in_sizes[0] * 4));
  float* c_traffic = (float*)(w + take((size_t)in_sizes[1] * 4));
  float* c_Wx_p = (float*)(w + take((size_t)in_sizes[5] * 4));
  float* c_Wh_p = (float*)(w + take((size_t)in_sizes[6] * 4));
  float* c_b_p  = (float*)(w + take((size_t)in_sizes[7] * 4));
  float* c_Wx_e = (float*)(w + take((size_t)in_sizes[8] * 4));
  float* c_Wh_e = (float*)(w + take((size_t)in_sizes[9] * 4));
  float* c_b_e  = (float*)(w + take((size_t)in_sizes[10] * 4));
  float* c_Wr1  = (float*)(w + take((size_t)in_sizes[11] * 4));
  float* c_br1  = (float*)(w + take((size_t)in_sizes[12] * 4));
  float* c_Wr2  = (float*)(w + take((size_t)in_sizes[13] * 4));
  float* c_br2  = (float*)(w + take((size_t)in_sizes[14] * 4));
  float* c_Wf   = (float*)(w + take((size_t)in_sizes[15] * 4));
  float* c_bf   = (float*)(w + take((size_t)in_sizes[16] * 4));
  int* cnt    = (int*)(w + take((size_t)n_links * 4));
  int* base   = (int*)(w + take((size_t)n_links * 4));
  int* cursor = (int*)(w + take((size_t)n_links * 4));
  int* pos_of = (int*)(w + take((size_t)E * 4));

  size_t rem = (ws_size > off) ? (ws_size - off) : 0;
  int mmode;
  ushort_t* mH = nullptr;
  if (rem >= (size_t)E * 64 * 2 + 256) { mmode = 1; mH = (ushort_t*)(w + take((size_t)E * 64 * 2)); }
  else mmode = 2;

  detect_dtype<<<1, 64, 0, stream>>>((const uint_t*)d_in[0], flag);

  ConvDesc cd;
  float* dsts[NARR] = {c_caps, c_traffic, c_Wx_p, c_Wh_p, c_b_p, c_Wx_e, c_Wh_e, c_b_e,
                       c_Wr1, c_br1, c_Wr2, c_br2, c_Wf, c_bf};
  int    srcs[NARR] = {0, 1, 5, 6, 7, 8, 9, 10, 11, 12, 13, 14, 15, 16};
  int nblk = 0;
  for (int a = 0; a < NARR; ++a) {
    cd.src[a] = d_in[srcs[a]];
    cd.dst[a] = dsts[a];
    cd.n[a] = in_sizes[srcs[a]];
    cd.blk0[a] = nblk;
    nblk += (cd.n[a] + 255) / 256;
  }
  cd.blk0[NARR] = nblk;
  conv_all<<<nblk, 256, 0, stream>>>(cd, flag);

  {
    long total = (long)(n_links + n_paths) * 64;
    int blocks = (int)((total + 255) / 256);
    init_states<<<blocks, 256, 0, stream>>>(c_caps, c_traffic, linkHL, path_state,
                                            n_links, n_paths);
  }
  {
    PackAll P;
    const float* As[8] = {c_Wx_p, c_Wx_p, c_Wh_p, c_Wx_e, c_Wx_e, c_Wh_e, c_Wr1, c_Wr2};
    const float* Bs[8] = {c_Wh_p, c_Wx_p, c_Wh_p, c_Wh_e, c_Wx_e, c_Wh_e, c_Wr1, c_Wr2};
    ushort_t* dH[8] = {wzrH_p, wcH_p, wcH_p + 4096, wzrH_e, wcH_e, wcH_e + 4096, wr1H, wr2H};
    ushort_t* dL[8] = {wzrL_p, wcL_p, wcL_p + 4096, wzrL_e, wcL_e, wcL_e + 4096, wr1L, wr2L};
    int srcN[8]   = {192, 192, 192, 192, 192, 192, 256, 256};
    int colOff[8] = {0, 128, 128, 0, 128, 128, 0, 0};
    int splitK[8] = {64, 64, 64, 64, 64, 64, 64, 256};
    int nCk[8]    = {4, 2, 2, 4, 2, 2, 2, 8};
    int NT[8]     = {8, 4, 4, 8, 4, 4, 16, 16};
    int pb = 0;
    for (int a = 0; a < 8; ++a) {
      P.A[a] = As[a]; P.B[a] = Bs[a]; P.dH[a] = dH[a]; P.dL[a] = dL[a];
      P.srcN[a] = srcN[a]; P.colOff[a] = colOff[a]; P.splitK[a] = splitK[a];
      P.nCk[a] = nCk[a]; P.NT[a] = NT[a]; P.blk0[a] = pb;
      pb += nCk[a] * NT[a] * 2;
    }
    P.blk0[8] = pb;
    pack_all<<<pb, 256, 0, stream>>>(P);
  }

  const int* links = (const int*)d_in[2];
  if (mmode == 1) {
    (void)hipMemsetAsync(cnt, 0, (size_t)n_links * 4, stream);
    hist_k<<<(E + 255) / 256, 256, 0, stream>>>(links, cnt, E);
    scan_k<<<1, 256, 0, stream>>>(cnt, base, cursor, n_links);
    fill_k<<<(E + 255) / 256, 256, 0, stream>>>(links, cursor, pos_of, E);
  }

  int grid_bf = (n_paths + 16 * PWB - 1) / (16 * PWB);
  int slots   = (n_paths + 16 * PW - 1) / (16 * PW);      // 481
  int gridF   = slots < 256 ? slots : 256;
  int nGroups = (slots + gridF - 1) / gridF;               // 2

  for (int it = 0; it < 3; ++it) {
    int store_m = (it < 2) ? 1 : 0;
    if (mmode == 2 && store_m) (void)hipMemsetAsync(agg, 0, (size_t)n_links * 64 * 4, stream);
    path_kernel_bf16<<<grid_bf, 448, 0, stream>>>(
        links, linkHL, path_state, mH, mmode, store_m, pos_of, agg,
        wzrH_p, wcH_p, c_b_p, flag, n_paths);
    path_kernel_f32<<<gridF, 832, 0, stream>>>(
        links, linkHL, path_state, mH, mmode, store_m, pos_of, agg,
        wzrH_p, wzrL_p, wcH_p, wcL_p, c_b_p, flag, n_paths, nGroups);
    if (it < 2) {
      if (mmode == 1)
        agg_kernel<<<(n_links + 3) / 4, 256, 0, stream>>>(mH, base, cnt, agg, n_links);
      link_kernel<<<n_links / 80, 320, 0, stream>>>(agg, linkHL,
                                                    wzrH_e, wzrL_e, wcH_e, wcL_e, c_b_e, flag);
    }
  }
  readout_kernel<<<(n_paths + 16 * RW - 1) / (16 * RW), 512, 0, stream>>>(
      path_state, n_paths, wr1H, wr1L, wr2H, wr2L,
      c_br1, c_br2, c_Wf, c_bf, d_out, flag);
}